// Round 6
// baseline (4917.315 us; speedup 1.0000x reference)
//
#include <hip/hip_runtime.h>

#define BATCH  4096
#define HID    1024
#define NOUT   64
#define TSTEPS 25
#define KA     1088   // 64 (y_prev) + 1024 (h1)
#define KB     2048   // 1024 (h1) + 1024 (h2)
#define LDY    1600   // TSTEPS * NOUT

typedef __attribute__((ext_vector_type(8))) __bf16 bf16x8;
typedef __attribute__((ext_vector_type(4))) float  floatx4;

__device__ __forceinline__ unsigned short f2bf(float f) {
    union { float f; unsigned u; } v; v.f = f;
    unsigned r = v.u + 0x7fffu + ((v.u >> 16) & 1u);
    return (unsigned short)(r >> 16);
}
__device__ __forceinline__ float rcpf(float x) { return __builtin_amdgcn_rcpf(x); }
__device__ __forceinline__ float sigmf(float x) { return rcpf(1.0f + __expf(-x)); }
__device__ __forceinline__ float tanh_fast(float x) {
    float ax = fabsf(x);
    float e  = __expf(-2.0f * ax);
    float t  = (1.0f - e) * rcpf(1.0f + e);
    return copysignf(t, x);
}

#define GLDS16(gp, lp) __builtin_amdgcn_global_load_lds( \
    (const __attribute__((address_space(1))) void*)(gp), \
    (__attribute__((address_space(3))) void*)(lp), 16, 0, 0)

// Fused GEMM + LSTM cell, v4: block = 2 waves (128 thr), tile 128(M)x128(N),
// wave tile 128x64 (acc[8][4] -> 32 MFMA : 12 ds_read_b128 per BK=32).
// LDS 2x16KB double-buffer = 32 KB -> 4 blocks/CU = 4 INDEPENDENT barrier
// domains (v3 had 2 -> barriers on all CU waves aligned, no mutual overlap;
// m97's 874 TF came from 3 blocks/CU inter-block overlap). Grid 32x32 = 1024
// blocks = exactly 4/CU, zero tail.
// G = X[4096,K] @ W[4096,K]^T (W rows gate-major: gate*HID + j), then per (b,j):
// gates = G + ginit[b*gstride + j*4 + gate]   (gate-interleaved float4 layout),
// c' = sig(f)*c + sig(i)*tanh(g); h = sig(o)*tanh(c'); h -> d1/d2 (bf16), dfp (fp32).
__global__ __launch_bounds__(128, 2) void lstm_gate_gemm(
    const unsigned short* __restrict__ X, int K,
    const unsigned short* __restrict__ W,
    const float* __restrict__ ginit, int gstride,
    float* __restrict__ cell,
    unsigned short* __restrict__ d1, int ld1, int off1,
    unsigned short* __restrict__ d2, int ld2, int off2,
    float* __restrict__ dfp)
{
    // buf: 16 KB = A(128x32 bf16, 8K) + B(128x32 bf16, 8K); two buffers.
    __shared__ __align__(16) char smem[32768];

    const int tid  = threadIdx.x;
    const int lane = tid & 63;
    const int w    = tid >> 6;          // wave 0/1 -> N col half
    const int q    = lane >> 4;
    const int lr   = lane & 15;
    const int m0   = blockIdx.x * 128;
    const int j0   = blockIdx.y * 32;

    // staging: slot s (16B): s<512 -> A row s>>2 (0..127), else B row (s-512)>>2.
    // k-group (s&3)^((row>>1)&3) xor swizzle. 8 slots per thread.
    const unsigned short* srcS[8];
    char* ldsS[8];
#pragma unroll
    for (int e = 0; e < 8; ++e) {
        int s = e * 128 + tid;
        int kg, row;
        if (s < 512) {
            row = s >> 2;
            kg  = (s & 3) ^ ((row >> 1) & 3);
            srcS[e] = X + (size_t)(m0 + row) * K + kg * 8;
        } else {
            int t = s - 512;
            row = t >> 2;
            kg  = (t & 3) ^ ((row >> 1) & 3);
            int jj = row >> 2, gate = row & 3;
            srcS[e] = W + (size_t)(gate * HID + j0 + jj) * K + kg * 8;
        }
        ldsS[e] = smem + (size_t)s * 16;    // wave-uniform base + lane*16 within each e
    }

    // fragment LDS offsets within a buffer (same swizzle)
    unsigned offA[8], offB[4];
#pragma unroll
    for (int i = 0; i < 8; ++i) {
        int ra = i * 16 + lr;                            // 0..127 (both waves share A)
        offA[i] = (unsigned)((ra * 4 + (q ^ ((ra >> 1) & 3))) * 16);
    }
#pragma unroll
    for (int j = 0; j < 4; ++j) {
        int rb = w * 64 + j * 16 + lr;                   // 0..127
        offB[j] = (unsigned)(8192 + (rb * 4 + (q ^ ((rb >> 1) & 3))) * 16);
    }

    floatx4 acc[8][4];
#pragma unroll
    for (int i = 0; i < 8; ++i)
#pragma unroll
        for (int j = 0; j < 4; ++j)
            acc[i][j] = floatx4{0.f, 0.f, 0.f, 0.f};

    const int kiters = K >> 5;

    // prologue: stage kt=0 into buf0
#pragma unroll
    for (int e = 0; e < 8; ++e)
        GLDS16(srcS[e], ldsS[e]);

    for (int kt = 0; kt < kiters; ++kt) {
        __syncthreads();   // drains buf[kt&1] loads (issued one MFMA phase ago)
        const int cur = (kt & 1) * 16384;
        if (kt + 1 < kiters) {
            const int koff = (kt + 1) * 32;
            const int nxt  = ((kt + 1) & 1) * 16384;
#pragma unroll
            for (int e = 0; e < 8; ++e)
                GLDS16(srcS[e] + koff, ldsS[e] + nxt);
        }
        bf16x8 bv[4];
#pragma unroll
        for (int j = 0; j < 4; ++j) bv[j] = *(const bf16x8*)(smem + cur + offB[j]);
#pragma unroll
        for (int i = 0; i < 8; ++i) {
            bf16x8 av = *(const bf16x8*)(smem + cur + offA[i]);
#pragma unroll
            for (int j = 0; j < 4; ++j)
                acc[i][j] = __builtin_amdgcn_mfma_f32_16x16x32_bf16(av, bv[j], acc[i][j], 0, 0, 0);
        }
    }

    // ---- epilogue: per-wave LDS transpose of 16x64 slabs, then cell update.
    // Barriers fence write-phase vs read-phase (compiler memory ordering —
    // scalar float stores vs float4 loads are not TBAA-ordered without them).
    const int jg = j0 + w * 16 + lr;
    float* scratch = (float*)(void*)smem + w * 1024;     // 4 KB per wave, wave-private

#pragma unroll
    for (int i = 0; i < 8; ++i) {
        __syncthreads();
#pragma unroll
        for (int j = 0; j < 4; ++j)
#pragma unroll
            for (int r = 0; r < 4; ++r)
                scratch[(q * 4 + r) * 64 + j * 16 + lr] = acc[i][j][r];  // C/D: row=q*4+r, col=lr
        __syncthreads();
#pragma unroll
        for (int p = 0; p < 4; ++p) {
            int row = q + p * 4;
            const float4 g = *(const float4*)(scratch + row * 64 + lr * 4);  // (i,f,g,o)
            int b = m0 + i * 16 + row;
            const float4 gi = *(const float4*)(ginit + (size_t)b * gstride + (size_t)jg * 4);
            float iv = sigmf(g.x + gi.x);
            float fv = sigmf(g.y + gi.y);
            float gv = tanh_fast(g.z + gi.z);
            float ov = sigmf(g.w + gi.w);
            size_t ci = (size_t)b * HID + jg;
            float cn = fv * cell[ci] + iv * gv;
            cell[ci] = cn;
            float hv = ov * tanh_fast(cn);
            unsigned short hb = f2bf(hv);
            d1[(size_t)b * ld1 + off1 + jg] = hb;
            if (d2)  d2[(size_t)b * ld2 + off2 + jg] = hb;
            if (dfp) dfp[(size_t)b * HID + jg] = hv;
        }
    }
}

// ---- S0 = static @ W_ih0[:, :128]^T + b0, fp32, gate-interleaved output [b][j*4+gate]
// WT4 layout: wt4[k*4096 + j*4 + gate] = W_ih0[gate*1024+j][k], k<128
__global__ __launch_bounds__(256) void s0_gemm_tiled(
    const float* __restrict__ stat, const float* __restrict__ wt4,
    const float* __restrict__ bias4, float* __restrict__ s0)
{
    __shared__ float xl[32 * 128];   // 16 KB: 32 batch rows of static input
    const int tid = threadIdx.x;
    const int j0 = blockIdx.x * 64;
    const int b0 = blockIdx.y * 32;
#pragma unroll
    for (int r = 0; r < 4; ++r) {
        int f4 = r * 256 + tid;
        *(float4*)(xl + f4 * 4) = *(const float4*)(stat + (size_t)b0 * 128 + f4 * 4);
    }
    __syncthreads();
    const int j  = j0 + (tid & 63);
    const int wv = tid >> 6;
    float4 acc[8];
#pragma unroll
    for (int bb = 0; bb < 8; ++bb) acc[bb] = float4{0.f, 0.f, 0.f, 0.f};
#pragma unroll 4
    for (int k = 0; k < 128; ++k) {
        float4 w4 = *(const float4*)(wt4 + (size_t)k * 4096 + j * 4);
#pragma unroll
        for (int bb = 0; bb < 8; ++bb) {
            float xv = xl[(wv * 8 + bb) * 128 + k];
            acc[bb].x += xv * w4.x; acc[bb].y += xv * w4.y;
            acc[bb].z += xv * w4.z; acc[bb].w += xv * w4.w;
        }
    }
    float4 bi = *(const float4*)(bias4 + (size_t)j * 4);
#pragma unroll
    for (int bb = 0; bb < 8; ++bb) {
        int b = b0 + wv * 8 + bb;
        float4 o;
        o.x = acc[bb].x + bi.x; o.y = acc[bb].y + bi.y;
        o.z = acc[bb].z + bi.z; o.w = acc[bb].w + bi.w;
        *(float4*)(s0 + (size_t)b * 4096 + j * 4) = o;
    }
}

// y = h2_f32 @ Wout^T + bout (fp32); WoutT layout wt[k*64+o]; h2 staged in LDS.
__global__ __launch_bounds__(256) void out_gemm(
    const float* __restrict__ h2, const float* __restrict__ wt,
    const float* __restrict__ bout, float* __restrict__ y,
    unsigned short* __restrict__ xn)
{
    __shared__ float hl[8 * 1024];   // 32 KB: 8 h2 rows
    const int tid = threadIdx.x;
    const int b0 = blockIdx.x * 8;
#pragma unroll
    for (int r = 0; r < 8; ++r) {
        int f4 = r * 256 + tid;
        *(float4*)(hl + f4 * 4) = *(const float4*)(h2 + (size_t)b0 * 1024 + f4 * 4);
    }
    __syncthreads();
    const int o  = tid & 63;
    const int wv = tid >> 6;
    float acc0 = 0.f, acc1 = 0.f;
#pragma unroll 8
    for (int k = 0; k < 1024; ++k) {
        float wvv = wt[k * 64 + o];
        acc0 += hl[(wv * 2 + 0) * 1024 + k] * wvv;
        acc1 += hl[(wv * 2 + 1) * 1024 + k] * wvv;
    }
    float bo = bout[o];
    int b = b0 + wv * 2;
    float y0 = acc0 + bo, y1 = acc1 + bo;
    y[(size_t)b * LDY + o] = y0;
    y[(size_t)(b + 1) * LDY + o] = y1;
    xn[(size_t)b * KA + o] = f2bf(y0);
    xn[(size_t)(b + 1) * KA + o] = f2bf(y1);
}

// WT4[k*4096 + j*4 + gate] = W_ih0[(gate*1024+j)*192 + k]  (k < 128)
__global__ void build_wt0(const float* __restrict__ wih, float* __restrict__ wt4)
{
    int idx = blockIdx.x * 256 + threadIdx.x;   // 524288
    int gate = idx & 3, j = (idx >> 2) & 1023, k = idx >> 12;
    wt4[idx] = wih[(size_t)(gate * 1024 + j) * 192 + k];
}

// WoutT[k*64+o] = Wout[o*1024+k]
__global__ void build_woutT(const float* __restrict__ wout, float* __restrict__ wt)
{
    int idx = blockIdx.x * 256 + threadIdx.x;   // 65536
    int o = idx & 63, k = idx >> 6;
    wt[idx] = wout[(size_t)o * 1024 + k];
}

// interleaved bias: out[j*4+gate] = a[gate*1024+j] + b[gate*1024+j]
__global__ void build_bias(const float* __restrict__ a, const float* __restrict__ b,
                           float* __restrict__ o)
{
    int idx = blockIdx.x * 256 + threadIdx.x;   // 4096
    int gate = idx & 3, j = idx >> 2;
    int n = gate * 1024 + j;
    o[idx] = a[n] + b[n];
}

// W0[n][0:64] = W_ih0[n][128:192] (y-feedback cols), W0[n][64:1088] = W_hh0[n][:]
__global__ __launch_bounds__(256) void build_w0(
    const float* __restrict__ wih, const float* __restrict__ whh,
    unsigned short* __restrict__ w0)
{
    int idx = blockIdx.x * 256 + threadIdx.x;   // 4096*272 exact
    int n = idx / 272;
    int c = (idx - n * 272) * 4;
    float4 v;
    if (c < 64) v = *(const float4*)(wih + (size_t)n * 192 + 128 + c);
    else        v = *(const float4*)(whh + (size_t)n * 1024 + (c - 64));
    ushort4 o;
    o.x = f2bf(v.x); o.y = f2bf(v.y); o.z = f2bf(v.z); o.w = f2bf(v.w);
    *(ushort4*)(w0 + (size_t)n * KA + c) = o;
}

// W1[n][0:1024] = W_ih1[n][:], W1[n][1024:2048] = W_hh1[n][:]
__global__ __launch_bounds__(256) void build_w1(
    const float* __restrict__ wih, const float* __restrict__ whh,
    unsigned short* __restrict__ w1)
{
    int idx = blockIdx.x * 256 + threadIdx.x;   // 4096*512 exact
    int n = idx >> 9;
    int c = (idx & 511) * 4;
    float4 v;
    if (c < 1024) v = *(const float4*)(wih + (size_t)n * 1024 + c);
    else          v = *(const float4*)(whh + (size_t)n * 1024 + (c - 1024));
    ushort4 o;
    o.x = f2bf(v.x); o.y = f2bf(v.y); o.z = f2bf(v.z); o.w = f2bf(v.w);
    *(ushort4*)(w1 + (size_t)n * KB + c) = o;
}

extern "C" void kernel_launch(void* const* d_in, const int* in_sizes, int n_in,
                              void* d_out, int out_size, void* d_ws, size_t ws_size,
                              hipStream_t stream)
{
    (void)in_sizes; (void)n_in; (void)out_size; (void)ws_size;
    const float* static_in = (const float*)d_in[0];
    const float* Wih0 = (const float*)d_in[1];
    const float* Whh0 = (const float*)d_in[2];
    const float* bih0 = (const float*)d_in[3];
    const float* bhh0 = (const float*)d_in[4];
    const float* Wih1 = (const float*)d_in[5];
    const float* Whh1 = (const float*)d_in[6];
    const float* bih1 = (const float*)d_in[7];
    const float* bhh1 = (const float*)d_in[8];
    const float* Wout = (const float*)d_in[9];
    const float* bout = (const float*)d_in[10];
    float* out = (float*)d_out;

    char* p = (char*)d_ws;
    size_t off = 0;
    auto take = [&](size_t n) { char* r = p + off; off += (n + 255) & ~(size_t)255; return r; };

    unsigned short* W0   = (unsigned short*)take((size_t)4096 * KA * 2);
    unsigned short* W1   = (unsigned short*)take((size_t)4096 * KB * 2);
    float*          B1b  = (float*)take(4096 * 4);
    float*          B0b  = (float*)take(4096 * 4);
    float*          WT0  = (float*)take((size_t)128 * 4096 * 4);
    float*          WoT  = (float*)take((size_t)1024 * 64 * 4);
    float*          S0   = (float*)take((size_t)BATCH * 4096 * 4);
    float*          H2f  = (float*)take((size_t)BATCH * HID * 4);
    float*          C1   = (float*)take((size_t)BATCH * HID * 4);
    float*          C2   = (float*)take((size_t)BATCH * HID * 4);
    unsigned short* X0a  = (unsigned short*)take((size_t)BATCH * KA * 2);
    unsigned short* X0b  = (unsigned short*)take((size_t)BATCH * KA * 2);
    unsigned short* X1a  = (unsigned short*)take((size_t)BATCH * KB * 2);
    unsigned short* X1b  = (unsigned short*)take((size_t)BATCH * KB * 2);
    // total ~190 MiB

    hipMemsetAsync(C1, 0, (size_t)BATCH * HID * 4, stream);
    hipMemsetAsync(C2, 0, (size_t)BATCH * HID * 4, stream);
    hipMemsetAsync(X0a, 0, (size_t)BATCH * KA * 2, stream);   // y0 = h1_0 = 0
    hipMemsetAsync(X1a, 0, (size_t)BATCH * KB * 2, stream);   // h2_0 = 0

    build_w0<<<4352, 256, 0, stream>>>(Wih0, Whh0, W0);
    build_w1<<<8192, 256, 0, stream>>>(Wih1, Whh1, W1);
    build_wt0<<<2048, 256, 0, stream>>>(Wih0, WT0);
    build_woutT<<<256, 256, 0, stream>>>(Wout, WoT);
    build_bias<<<16, 256, 0, stream>>>(bih0, bhh0, B0b);
    build_bias<<<16, 256, 0, stream>>>(bih1, bhh1, B1b);
    s0_gemm_tiled<<<dim3(16, 128), 256, 0, stream>>>(static_in, WT0, B0b, S0);

    dim3 grid(32, 32);   // 1024 blocks of 128 thr = exactly 4 per CU
    for (int t = 0; t < TSTEPS; ++t) {
        unsigned short* X0c = (t & 1) ? X0b : X0a;
        unsigned short* X0n = (t & 1) ? X0a : X0b;
        unsigned short* X1c = (t & 1) ? X1b : X1a;
        unsigned short* X1n = (t & 1) ? X1a : X1b;
        // layer 0: gates = X0c @ W0^T + S0[b]; h1 -> X1c[:,0:1024] and X0n[:,64:1088]
        lstm_gate_gemm<<<grid, 128, 0, stream>>>(X0c, KA, W0, S0, 4096, C1,
                                                 X1c, KB, 0, X0n, KA, 64, nullptr);
        // layer 1: gates = X1c @ W1^T + b1 (interleaved); h2 -> X1n[:,1024:2048] + H2f
        lstm_gate_gemm<<<grid, 128, 0, stream>>>(X1c, KB, W1, B1b, 0, C2,
                                                 X1n, KB, 1024, nullptr, 0, 0, H2f);
        // y_t = H2f @ WoutT + bout -> out[:,t,:] and X0n[:,0:64]
        out_gemm<<<512, 256, 0, stream>>>(H2f, WoT, bout, out + t * NOUT, X0n);
    }
}

// Round 7
// 4865.194 us; speedup vs baseline: 1.0107x; 1.0107x over previous
//
#include <hip/hip_runtime.h>

#define BATCH  4096
#define HID    1024
#define NOUT   64
#define TSTEPS 25
#define KA     1088   // 64 (y_prev) + 1024 (h1)
#define KB     2048   // 1024 (h1) + 1024 (h2)
#define LDY    1600   // TSTEPS * NOUT

typedef __attribute__((ext_vector_type(8))) __bf16 bf16x8;
typedef __attribute__((ext_vector_type(4))) float  floatx4;

__device__ __forceinline__ unsigned short f2bf(float f) {
    union { float f; unsigned u; } v; v.f = f;
    unsigned r = v.u + 0x7fffu + ((v.u >> 16) & 1u);
    return (unsigned short)(r >> 16);
}
__device__ __forceinline__ float rcpf(float x) { return __builtin_amdgcn_rcpf(x); }
__device__ __forceinline__ float sigmf(float x) { return rcpf(1.0f + __expf(-x)); }
__device__ __forceinline__ float tanh_fast(float x) {
    float ax = fabsf(x);
    float e  = __expf(-2.0f * ax);
    float t  = (1.0f - e) * rcpf(1.0f + e);
    return copysignf(t, x);
}

#define GLDS16(gp, lp) __builtin_amdgcn_global_load_lds( \
    (const __attribute__((address_space(1))) void*)(gp), \
    (__attribute__((address_space(3))) void*)(lp), 16, 0, 0)

// Fused GEMM + LSTM cell, v5: m97-occupancy config. Block tile 128x128,
// 4 waves 2x2 of 64x64 (acc[4][4] = 64 AGPR -> ~136 regs -> 3 waves/SIMD ->
// 3 blocks/CU resident; v3/v4 ran only 2 waves/SIMD and measured 3.2x above
// pipe floors = latency-stall-bound). Double-buffered LDS 2x16KB, one barrier
// per kiter. Grid 32x32=1024 (m97's shape).
// G = X[4096,K] @ W[4096,K]^T (W rows gate-major: gate*HID + j), then per (b,j):
// gates = G + ginit[b*gstride + j*4 + gate]   (gate-interleaved float4 layout),
// c' = sig(f)*c + sig(i)*tanh(g); h = sig(o)*tanh(c'); h -> d1/d2 (bf16), dfp (fp32).
__global__ __launch_bounds__(256, 3) void lstm_gate_gemm(
    const unsigned short* __restrict__ X, int K,
    const unsigned short* __restrict__ W,
    const float* __restrict__ ginit, int gstride,
    float* __restrict__ cell,
    unsigned short* __restrict__ d1, int ld1, int off1,
    unsigned short* __restrict__ d2, int ld2, int off2,
    float* __restrict__ dfp)
{
    // buffer: A(128x32 bf16 = 8K) + B(8K) = 16 KB; two buffers = 32 KB.
    __shared__ __align__(16) char smem[32768];

    const int tid  = threadIdx.x;
    const int lane = tid & 63;
    const int w    = tid >> 6;
    const int q    = lane >> 4;
    const int lr   = lane & 15;
    const int wm   = w >> 1;            // M half (64 rows each)
    const int wn   = w & 1;             // N half (64 cols each)
    const int m0   = blockIdx.x * 128;
    const int j0   = blockIdx.y * 32;

    // staging: slot s (16B): s<512 -> A row s>>2 (0..127), else B row (s-512)>>2.
    // k-group (s&3)^((row>>1)&3) xor swizzle. 4 slots per thread.
    const unsigned short* srcS[4];
    char* ldsS[4];
#pragma unroll
    for (int e = 0; e < 4; ++e) {
        int s = e * 256 + tid;
        if (s < 512) {
            int row = s >> 2;
            int kg  = (s & 3) ^ ((row >> 1) & 3);
            srcS[e] = X + (size_t)(m0 + row) * K + kg * 8;
        } else {
            int t   = s - 512;
            int row = t >> 2;
            int kg  = (t & 3) ^ ((row >> 1) & 3);
            int jj = row >> 2, gate = row & 3;
            srcS[e] = W + (size_t)(gate * HID + j0 + jj) * K + kg * 8;
        }
        ldsS[e] = smem + (size_t)s * 16;
    }

    // fragment LDS offsets within a buffer (same swizzle)
    unsigned offA[4], offB[4];
#pragma unroll
    for (int i = 0; i < 4; ++i) {
        int ra = wm * 64 + i * 16 + lr;                  // 0..127
        offA[i] = (unsigned)((ra * 4 + (q ^ ((ra >> 1) & 3))) * 16);
        int rb = wn * 64 + i * 16 + lr;                  // 0..127
        offB[i] = (unsigned)(8192 + (rb * 4 + (q ^ ((rb >> 1) & 3))) * 16);
    }

    floatx4 acc[4][4];
#pragma unroll
    for (int i = 0; i < 4; ++i)
#pragma unroll
        for (int j = 0; j < 4; ++j)
            acc[i][j] = floatx4{0.f, 0.f, 0.f, 0.f};

    const int kiters = K >> 5;

    // prologue: stage kt=0 into buf0
#pragma unroll
    for (int e = 0; e < 4; ++e)
        GLDS16(srcS[e], ldsS[e]);

    for (int kt = 0; kt < kiters; ++kt) {
        __syncthreads();   // drains buf[kt&1] loads (issued one MFMA phase ago)
        const int cur = (kt & 1) * 16384;
        if (kt + 1 < kiters) {
            const int koff = (kt + 1) * 32;
            const int nxt  = ((kt + 1) & 1) * 16384;
#pragma unroll
            for (int e = 0; e < 4; ++e)
                GLDS16(srcS[e] + koff, ldsS[e] + nxt);
        }
        bf16x8 av[4], bv[4];
#pragma unroll
        for (int j = 0; j < 4; ++j) bv[j] = *(const bf16x8*)(smem + cur + offB[j]);
#pragma unroll
        for (int i = 0; i < 4; ++i) av[i] = *(const bf16x8*)(smem + cur + offA[i]);
#pragma unroll
        for (int i = 0; i < 4; ++i)
#pragma unroll
            for (int j = 0; j < 4; ++j)
                acc[i][j] = __builtin_amdgcn_mfma_f32_16x16x32_bf16(av[i], bv[j], acc[i][j], 0, 0, 0);
    }

    // ---- epilogue: per-wave LDS transpose of 16x64 slabs, then cell update.
    // Barriers fence write-phase vs read-phase (compiler memory ordering —
    // scalar float stores vs float4 loads are not TBAA-ordered without them).
    const int jg = j0 + wn * 16 + lr;
    float* scratch = (float*)(void*)smem + w * 1024;     // 4 KB per wave, wave-private

#pragma unroll
    for (int i = 0; i < 4; ++i) {
        __syncthreads();
#pragma unroll
        for (int j = 0; j < 4; ++j)
#pragma unroll
            for (int r = 0; r < 4; ++r)
                scratch[(q * 4 + r) * 64 + j * 16 + lr] = acc[i][j][r];  // C/D: row=q*4+r, col=lr
        __syncthreads();
#pragma unroll
        for (int p = 0; p < 4; ++p) {
            int row = q + p * 4;
            const float4 g = *(const float4*)(scratch + row * 64 + lr * 4);  // (i,f,g,o)
            int b = m0 + wm * 64 + i * 16 + row;
            const float4 gi = *(const float4*)(ginit + (size_t)b * gstride + (size_t)jg * 4);
            float iv = sigmf(g.x + gi.x);
            float fv = sigmf(g.y + gi.y);
            float gv = tanh_fast(g.z + gi.z);
            float ov = sigmf(g.w + gi.w);
            size_t ci = (size_t)b * HID + jg;
            float cn = fv * cell[ci] + iv * gv;
            cell[ci] = cn;
            float hv = ov * tanh_fast(cn);
            unsigned short hb = f2bf(hv);
            d1[(size_t)b * ld1 + off1 + jg] = hb;
            if (d2)  d2[(size_t)b * ld2 + off2 + jg] = hb;
            if (dfp) dfp[(size_t)b * HID + jg] = hv;
        }
    }
}

// ---- S0 = static @ W_ih0[:, :128]^T + b0, fp32, gate-interleaved output [b][j*4+gate]
// WT4 layout: wt4[k*4096 + j*4 + gate] = W_ih0[gate*1024+j][k], k<128
__global__ __launch_bounds__(256) void s0_gemm_tiled(
    const float* __restrict__ stat, const float* __restrict__ wt4,
    const float* __restrict__ bias4, float* __restrict__ s0)
{
    __shared__ float xl[32 * 128];   // 16 KB: 32 batch rows of static input
    const int tid = threadIdx.x;
    const int j0 = blockIdx.x * 64;
    const int b0 = blockIdx.y * 32;
#pragma unroll
    for (int r = 0; r < 4; ++r) {
        int f4 = r * 256 + tid;
        *(float4*)(xl + f4 * 4) = *(const float4*)(stat + (size_t)b0 * 128 + f4 * 4);
    }
    __syncthreads();
    const int j  = j0 + (tid & 63);
    const int wv = tid >> 6;
    float4 acc[8];
#pragma unroll
    for (int bb = 0; bb < 8; ++bb) acc[bb] = float4{0.f, 0.f, 0.f, 0.f};
#pragma unroll 4
    for (int k = 0; k < 128; ++k) {
        float4 w4 = *(const float4*)(wt4 + (size_t)k * 4096 + j * 4);
#pragma unroll
        for (int bb = 0; bb < 8; ++bb) {
            float xv = xl[(wv * 8 + bb) * 128 + k];
            acc[bb].x += xv * w4.x; acc[bb].y += xv * w4.y;
            acc[bb].z += xv * w4.z; acc[bb].w += xv * w4.w;
        }
    }
    float4 bi = *(const float4*)(bias4 + (size_t)j * 4);
#pragma unroll
    for (int bb = 0; bb < 8; ++bb) {
        int b = b0 + wv * 8 + bb;
        float4 o;
        o.x = acc[bb].x + bi.x; o.y = acc[bb].y + bi.y;
        o.z = acc[bb].z + bi.z; o.w = acc[bb].w + bi.w;
        *(float4*)(s0 + (size_t)b * 4096 + j * 4) = o;
    }
}

// y = h2_f32 @ Wout^T + bout (fp32); WoutT layout wt[k*64+o]; h2 staged in LDS.
__global__ __launch_bounds__(256) void out_gemm(
    const float* __restrict__ h2, const float* __restrict__ wt,
    const float* __restrict__ bout, float* __restrict__ y,
    unsigned short* __restrict__ xn)
{
    __shared__ float hl[8 * 1024];   // 32 KB: 8 h2 rows
    const int tid = threadIdx.x;
    const int b0 = blockIdx.x * 8;
#pragma unroll
    for (int r = 0; r < 8; ++r) {
        int f4 = r * 256 + tid;
        *(float4*)(hl + f4 * 4) = *(const float4*)(h2 + (size_t)b0 * 1024 + f4 * 4);
    }
    __syncthreads();
    const int o  = tid & 63;
    const int wv = tid >> 6;
    float acc0 = 0.f, acc1 = 0.f;
#pragma unroll 8
    for (int k = 0; k < 1024; ++k) {
        float wvv = wt[k * 64 + o];
        acc0 += hl[(wv * 2 + 0) * 1024 + k] * wvv;
        acc1 += hl[(wv * 2 + 1) * 1024 + k] * wvv;
    }
    float bo = bout[o];
    int b = b0 + wv * 2;
    float y0 = acc0 + bo, y1 = acc1 + bo;
    y[(size_t)b * LDY + o] = y0;
    y[(size_t)(b + 1) * LDY + o] = y1;
    xn[(size_t)b * KA + o] = f2bf(y0);
    xn[(size_t)(b + 1) * KA + o] = f2bf(y1);
}

// WT4[k*4096 + j*4 + gate] = W_ih0[(gate*1024+j)*192 + k]  (k < 128)
__global__ void build_wt0(const float* __restrict__ wih, float* __restrict__ wt4)
{
    int idx = blockIdx.x * 256 + threadIdx.x;   // 524288
    int gate = idx & 3, j = (idx >> 2) & 1023, k = idx >> 12;
    wt4[idx] = wih[(size_t)(gate * 1024 + j) * 192 + k];
}

// WoutT[k*64+o] = Wout[o*1024+k]
__global__ void build_woutT(const float* __restrict__ wout, float* __restrict__ wt)
{
    int idx = blockIdx.x * 256 + threadIdx.x;   // 65536
    int o = idx & 63, k = idx >> 6;
    wt[idx] = wout[(size_t)o * 1024 + k];
}

// interleaved bias: out[j*4+gate] = a[gate*1024+j] + b[gate*1024+j]
__global__ void build_bias(const float* __restrict__ a, const float* __restrict__ b,
                           float* __restrict__ o)
{
    int idx = blockIdx.x * 256 + threadIdx.x;   // 4096
    int gate = idx & 3, j = idx >> 2;
    int n = gate * 1024 + j;
    o[idx] = a[n] + b[n];
}

// W0[n][0:64] = W_ih0[n][128:192] (y-feedback cols), W0[n][64:1088] = W_hh0[n][:]
__global__ __launch_bounds__(256) void build_w0(
    const float* __restrict__ wih, const float* __restrict__ whh,
    unsigned short* __restrict__ w0)
{
    int idx = blockIdx.x * 256 + threadIdx.x;   // 4096*272 exact
    int n = idx / 272;
    int c = (idx - n * 272) * 4;
    float4 v;
    if (c < 64) v = *(const float4*)(wih + (size_t)n * 192 + 128 + c);
    else        v = *(const float4*)(whh + (size_t)n * 1024 + (c - 64));
    ushort4 o;
    o.x = f2bf(v.x); o.y = f2bf(v.y); o.z = f2bf(v.z); o.w = f2bf(v.w);
    *(ushort4*)(w0 + (size_t)n * KA + c) = o;
}

// W1[n][0:1024] = W_ih1[n][:], W1[n][1024:2048] = W_hh1[n][:]
__global__ __launch_bounds__(256) void build_w1(
    const float* __restrict__ wih, const float* __restrict__ whh,
    unsigned short* __restrict__ w1)
{
    int idx = blockIdx.x * 256 + threadIdx.x;   // 4096*512 exact
    int n = idx >> 9;
    int c = (idx & 511) * 4;
    float4 v;
    if (c < 1024) v = *(const float4*)(wih + (size_t)n * 1024 + c);
    else          v = *(const float4*)(whh + (size_t)n * 1024 + (c - 1024));
    ushort4 o;
    o.x = f2bf(v.x); o.y = f2bf(v.y); o.z = f2bf(v.z); o.w = f2bf(v.w);
    *(ushort4*)(w1 + (size_t)n * KB + c) = o;
}

extern "C" void kernel_launch(void* const* d_in, const int* in_sizes, int n_in,
                              void* d_out, int out_size, void* d_ws, size_t ws_size,
                              hipStream_t stream)
{
    (void)in_sizes; (void)n_in; (void)out_size; (void)ws_size;
    const float* static_in = (const float*)d_in[0];
    const float* Wih0 = (const float*)d_in[1];
    const float* Whh0 = (const float*)d_in[2];
    const float* bih0 = (const float*)d_in[3];
    const float* bhh0 = (const float*)d_in[4];
    const float* Wih1 = (const float*)d_in[5];
    const float* Whh1 = (const float*)d_in[6];
    const float* bih1 = (const float*)d_in[7];
    const float* bhh1 = (const float*)d_in[8];
    const float* Wout = (const float*)d_in[9];
    const float* bout = (const float*)d_in[10];
    float* out = (float*)d_out;

    char* p = (char*)d_ws;
    size_t off = 0;
    auto take = [&](size_t n) { char* r = p + off; off += (n + 255) & ~(size_t)255; return r; };

    unsigned short* W0   = (unsigned short*)take((size_t)4096 * KA * 2);
    unsigned short* W1   = (unsigned short*)take((size_t)4096 * KB * 2);
    float*          B1b  = (float*)take(4096 * 4);
    float*          B0b  = (float*)take(4096 * 4);
    float*          WT0  = (float*)take((size_t)128 * 4096 * 4);
    float*          WoT  = (float*)take((size_t)1024 * 64 * 4);
    float*          S0   = (float*)take((size_t)BATCH * 4096 * 4);
    float*          H2f  = (float*)take((size_t)BATCH * HID * 4);
    float*          C1   = (float*)take((size_t)BATCH * HID * 4);
    float*          C2   = (float*)take((size_t)BATCH * HID * 4);
    unsigned short* X0a  = (unsigned short*)take((size_t)BATCH * KA * 2);
    unsigned short* X0b  = (unsigned short*)take((size_t)BATCH * KA * 2);
    unsigned short* X1a  = (unsigned short*)take((size_t)BATCH * KB * 2);
    unsigned short* X1b  = (unsigned short*)take((size_t)BATCH * KB * 2);
    // total ~190 MiB

    hipMemsetAsync(C1, 0, (size_t)BATCH * HID * 4, stream);
    hipMemsetAsync(C2, 0, (size_t)BATCH * HID * 4, stream);
    hipMemsetAsync(X0a, 0, (size_t)BATCH * KA * 2, stream);   // y0 = h1_0 = 0
    hipMemsetAsync(X1a, 0, (size_t)BATCH * KB * 2, stream);   // h2_0 = 0

    build_w0<<<4352, 256, 0, stream>>>(Wih0, Whh0, W0);
    build_w1<<<8192, 256, 0, stream>>>(Wih1, Whh1, W1);
    build_wt0<<<2048, 256, 0, stream>>>(Wih0, WT0);
    build_woutT<<<256, 256, 0, stream>>>(Wout, WoT);
    build_bias<<<16, 256, 0, stream>>>(bih0, bhh0, B0b);
    build_bias<<<16, 256, 0, stream>>>(bih1, bhh1, B1b);
    s0_gemm_tiled<<<dim3(16, 128), 256, 0, stream>>>(static_in, WT0, B0b, S0);

    dim3 grid(32, 32);   // 1024 blocks of 256 thr, 3 resident/CU (m97 shape)
    for (int t = 0; t < TSTEPS; ++t) {
        unsigned short* X0c = (t & 1) ? X0b : X0a;
        unsigned short* X0n = (t & 1) ? X0a : X0b;
        unsigned short* X1c = (t & 1) ? X1b : X1a;
        unsigned short* X1n = (t & 1) ? X1a : X1b;
        // layer 0: gates = X0c @ W0^T + S0[b]; h1 -> X1c[:,0:1024] and X0n[:,64:1088]
        lstm_gate_gemm<<<grid, 256, 0, stream>>>(X0c, KA, W0, S0, 4096, C1,
                                                 X1c, KB, 0, X0n, KA, 64, nullptr);
        // layer 1: gates = X1c @ W1^T + b1 (interleaved); h2 -> X1n[:,1024:2048] + H2f
        lstm_gate_gemm<<<grid, 256, 0, stream>>>(X1c, KB, W1, B1b, 0, C2,
                                                 X1n, KB, 1024, nullptr, 0, 0, H2f);
        // y_t = H2f @ WoutT + bout -> out[:,t,:] and X0n[:,0:64]
        out_gemm<<<512, 256, 0, stream>>>(H2f, WoT, bout, out + t * NOUT, X0n);
    }
}

// Round 8
// 4368.931 us; speedup vs baseline: 1.1255x; 1.1136x over previous
//
#include <hip/hip_runtime.h>

#define BATCH  4096
#define HID    1024
#define NOUT   64
#define TSTEPS 25
#define KA     1088   // 64 (y_prev) + 1024 (h1)
#define KB     2048   // 1024 (h1) + 1024 (h2)
#define LDY    1600   // TSTEPS * NOUT

typedef __attribute__((ext_vector_type(8))) __bf16 bf16x8;
typedef __attribute__((ext_vector_type(4))) float  floatx4;

__device__ __forceinline__ unsigned short f2bf(float f) {
    union { float f; unsigned u; } v; v.f = f;
    unsigned r = v.u + 0x7fffu + ((v.u >> 16) & 1u);
    return (unsigned short)(r >> 16);
}
__device__ __forceinline__ float rcpf(float x) { return __builtin_amdgcn_rcpf(x); }
__device__ __forceinline__ float sigmf(float x) { return rcpf(1.0f + __expf(-x)); }
__device__ __forceinline__ float tanh_fast(float x) {
    float ax = fabsf(x);
    float e  = __expf(-2.0f * ax);
    float t  = (1.0f - e) * rcpf(1.0f + e);
    return copysignf(t, x);
}

#define GLDS16(gp, lp) __builtin_amdgcn_global_load_lds( \
    (const __attribute__((address_space(1))) void*)(gp), \
    (__attribute__((address_space(3))) void*)(lp), 16, 0, 0)

// Fused GEMM + LSTM cell, v6: TRAFFIC-MINIMIZING config. All v2-v5 variants
// (97-110 us) were staging-bandwidth bound: tiled demand 2*M*N*K*2B/tile ranked
// them exactly (~10 TB/s L2-miss/L3 delivery). So: block tile 256x256 (512 thr,
// 8 waves 2Mx4N of 128x64) -> 512 MB/dispatch (half of v5), grid 16x16=256 =
// exactly 1 block/CU, LDS dbuf 2x32KB=64KB. XCD swizzle (id&7 round-robin):
// each XCD owns a 4x8 region -> its 4 A-tiles (4MB) go L2-resident and B-tile
// re-reads are temporally adjacent -> L2-hot.
// G = X[4096,K] @ W[4096,K]^T (W rows gate-major: gate*HID + j), then per (b,j):
// gates = G + ginit[b*gstride + j*4 + gate]   (gate-interleaved float4 layout),
// c' = sig(f)*c + sig(i)*tanh(g); h = sig(o)*tanh(c'); h -> d1/d2 (bf16), dfp (fp32).
__global__ __launch_bounds__(512, 2) void lstm_gate_gemm(
    const unsigned short* __restrict__ X, int K,
    const unsigned short* __restrict__ W,
    const float* __restrict__ ginit, int gstride,
    float* __restrict__ cell,
    unsigned short* __restrict__ d1, int ld1, int off1,
    unsigned short* __restrict__ d2, int ld2, int off2,
    float* __restrict__ dfp)
{
    // buffer: A(256x32 bf16 = 16K) + B(256x32 = 16K) = 32 KB; two buffers.
    __shared__ __align__(16) char smem[65536];

    const int tid  = threadIdx.x;
    const int lane = tid & 63;
    const int w    = tid >> 6;          // 0..7
    const int q    = lane >> 4;
    const int lr   = lane & 15;
    const int wm   = w >> 2;            // M half (128 rows each)
    const int wn   = w & 3;             // N quarter (64 cols each)

    // XCD-aware swizzle: id&7 = XCD (round-robin dispatch), each XCD gets a
    // 4(x) x 8(y) block region, iterated x-fastest (B-tile re-reads adjacent).
    const int id  = blockIdx.y * 16 + blockIdx.x;
    const int xcd = id & 7;
    const int c   = id >> 3;                       // 0..31
    const int bx  = (xcd & 3) * 4 + (c & 3);       // 0..15
    const int by  = (xcd >> 2) * 8 + (c >> 2);     // 0..15
    const int m0  = bx * 256;
    const int j0  = by * 64;

    // staging: slot s (16B): s<1024 -> A row s>>2 (0..255), else B row (s-1024)>>2.
    // k-group (s&3)^((row>>1)&3) xor swizzle. 4 slots per thread.
    const unsigned short* srcS[4];
    char* ldsS[4];
#pragma unroll
    for (int e = 0; e < 4; ++e) {
        int s = e * 512 + tid;
        if (s < 1024) {
            int row = s >> 2;
            int kg  = (s & 3) ^ ((row >> 1) & 3);
            srcS[e] = X + (size_t)(m0 + row) * K + kg * 8;
        } else {
            int t   = s - 1024;
            int row = t >> 2;
            int kg  = (t & 3) ^ ((row >> 1) & 3);
            int jj = row >> 2, gate = row & 3;
            srcS[e] = W + (size_t)(gate * HID + j0 + jj) * K + kg * 8;
        }
        ldsS[e] = smem + (size_t)s * 16;
    }

    // fragment LDS offsets within a buffer (same swizzle)
    unsigned offA[8], offB[4];
#pragma unroll
    for (int i = 0; i < 8; ++i) {
        int ra = wm * 128 + i * 16 + lr;                 // 0..255
        offA[i] = (unsigned)((ra * 4 + (q ^ ((ra >> 1) & 3))) * 16);
    }
#pragma unroll
    for (int j = 0; j < 4; ++j) {
        int rb = wn * 64 + j * 16 + lr;                  // 0..255
        offB[j] = (unsigned)(16384 + (rb * 4 + (q ^ ((rb >> 1) & 3))) * 16);
    }

    floatx4 acc[8][4];
#pragma unroll
    for (int i = 0; i < 8; ++i)
#pragma unroll
        for (int j = 0; j < 4; ++j)
            acc[i][j] = floatx4{0.f, 0.f, 0.f, 0.f};

    const int kiters = K >> 5;

    // prologue: stage kt=0 into buf0
#pragma unroll
    for (int e = 0; e < 4; ++e)
        GLDS16(srcS[e], ldsS[e]);

    for (int kt = 0; kt < kiters; ++kt) {
        __syncthreads();   // drains buf[kt&1] loads (issued one MFMA phase ago)
        const int cur = (kt & 1) * 32768;
        if (kt + 1 < kiters) {
            const int koff = (kt + 1) * 32;
            const int nxt  = ((kt + 1) & 1) * 32768;
#pragma unroll
            for (int e = 0; e < 4; ++e)
                GLDS16(srcS[e] + koff, ldsS[e] + nxt);
        }
        bf16x8 bv[4];
#pragma unroll
        for (int j = 0; j < 4; ++j) bv[j] = *(const bf16x8*)(smem + cur + offB[j]);
#pragma unroll
        for (int i = 0; i < 8; ++i) {
            bf16x8 av = *(const bf16x8*)(smem + cur + offA[i]);
#pragma unroll
            for (int j = 0; j < 4; ++j)
                acc[i][j] = __builtin_amdgcn_mfma_f32_16x16x32_bf16(av, bv[j], acc[i][j], 0, 0, 0);
        }
    }

    // ---- epilogue: per-wave LDS transpose of 16x64 slabs, then cell update.
    // Barriers fence write-phase vs read-phase (compiler memory ordering —
    // scalar float stores vs float4 loads are not TBAA-ordered without them).
    const int jg = j0 + wn * 16 + lr;
    float* scratch = (float*)(void*)smem + w * 1024;     // 4 KB per wave, wave-private

#pragma unroll
    for (int i = 0; i < 8; ++i) {
        __syncthreads();
#pragma unroll
        for (int j = 0; j < 4; ++j)
#pragma unroll
            for (int r = 0; r < 4; ++r)
                scratch[(q * 4 + r) * 64 + j * 16 + lr] = acc[i][j][r];  // C/D: row=q*4+r, col=lr
        __syncthreads();
#pragma unroll
        for (int p = 0; p < 4; ++p) {
            int row = q + p * 4;
            const float4 g = *(const float4*)(scratch + row * 64 + lr * 4);  // (i,f,g,o)
            int b = m0 + wm * 128 + i * 16 + row;
            const float4 gi = *(const float4*)(ginit + (size_t)b * gstride + (size_t)jg * 4);
            float iv = sigmf(g.x + gi.x);
            float fv = sigmf(g.y + gi.y);
            float gv = tanh_fast(g.z + gi.z);
            float ov = sigmf(g.w + gi.w);
            size_t ci = (size_t)b * HID + jg;
            float cn = fv * cell[ci] + iv * gv;
            cell[ci] = cn;
            float hv = ov * tanh_fast(cn);
            unsigned short hb = f2bf(hv);
            d1[(size_t)b * ld1 + off1 + jg] = hb;
            if (d2)  d2[(size_t)b * ld2 + off2 + jg] = hb;
            if (dfp) dfp[(size_t)b * HID + jg] = hv;
        }
    }
}

// ---- S0 = static @ W_ih0[:, :128]^T + b0, fp32, gate-interleaved output [b][j*4+gate]
// WT4 layout: wt4[k*4096 + j*4 + gate] = W_ih0[gate*1024+j][k], k<128
__global__ __launch_bounds__(256) void s0_gemm_tiled(
    const float* __restrict__ stat, const float* __restrict__ wt4,
    const float* __restrict__ bias4, float* __restrict__ s0)
{
    __shared__ float xl[32 * 128];   // 16 KB: 32 batch rows of static input
    const int tid = threadIdx.x;
    const int j0 = blockIdx.x * 64;
    const int b0 = blockIdx.y * 32;
#pragma unroll
    for (int r = 0; r < 4; ++r) {
        int f4 = r * 256 + tid;
        *(float4*)(xl + f4 * 4) = *(const float4*)(stat + (size_t)b0 * 128 + f4 * 4);
    }
    __syncthreads();
    const int j  = j0 + (tid & 63);
    const int wv = tid >> 6;
    float4 acc[8];
#pragma unroll
    for (int bb = 0; bb < 8; ++bb) acc[bb] = float4{0.f, 0.f, 0.f, 0.f};
#pragma unroll 4
    for (int k = 0; k < 128; ++k) {
        float4 w4 = *(const float4*)(wt4 + (size_t)k * 4096 + j * 4);
#pragma unroll
        for (int bb = 0; bb < 8; ++bb) {
            float xv = xl[(wv * 8 + bb) * 128 + k];
            acc[bb].x += xv * w4.x; acc[bb].y += xv * w4.y;
            acc[bb].z += xv * w4.z; acc[bb].w += xv * w4.w;
        }
    }
    float4 bi = *(const float4*)(bias4 + (size_t)j * 4);
#pragma unroll
    for (int bb = 0; bb < 8; ++bb) {
        int b = b0 + wv * 8 + bb;
        float4 o;
        o.x = acc[bb].x + bi.x; o.y = acc[bb].y + bi.y;
        o.z = acc[bb].z + bi.z; o.w = acc[bb].w + bi.w;
        *(float4*)(s0 + (size_t)b * 4096 + j * 4) = o;
    }
}

// y = h2_f32 @ Wout^T + bout (fp32); WoutT layout wt[k*64+o]; h2 staged in LDS.
__global__ __launch_bounds__(256) void out_gemm(
    const float* __restrict__ h2, const float* __restrict__ wt,
    const float* __restrict__ bout, float* __restrict__ y,
    unsigned short* __restrict__ xn)
{
    __shared__ float hl[8 * 1024];   // 32 KB: 8 h2 rows
    const int tid = threadIdx.x;
    const int b0 = blockIdx.x * 8;
#pragma unroll
    for (int r = 0; r < 8; ++r) {
        int f4 = r * 256 + tid;
        *(float4*)(hl + f4 * 4) = *(const float4*)(h2 + (size_t)b0 * 1024 + f4 * 4);
    }
    __syncthreads();
    const int o  = tid & 63;
    const int wv = tid >> 6;
    float acc0 = 0.f, acc1 = 0.f;
#pragma unroll 8
    for (int k = 0; k < 1024; ++k) {
        float wvv = wt[k * 64 + o];
        acc0 += hl[(wv * 2 + 0) * 1024 + k] * wvv;
        acc1 += hl[(wv * 2 + 1) * 1024 + k] * wvv;
    }
    float bo = bout[o];
    int b = b0 + wv * 2;
    float y0 = acc0 + bo, y1 = acc1 + bo;
    y[(size_t)b * LDY + o] = y0;
    y[(size_t)(b + 1) * LDY + o] = y1;
    xn[(size_t)b * KA + o] = f2bf(y0);
    xn[(size_t)(b + 1) * KA + o] = f2bf(y1);
}

// WT4[k*4096 + j*4 + gate] = W_ih0[(gate*1024+j)*192 + k]  (k < 128)
__global__ void build_wt0(const float* __restrict__ wih, float* __restrict__ wt4)
{
    int idx = blockIdx.x * 256 + threadIdx.x;   // 524288
    int gate = idx & 3, j = (idx >> 2) & 1023, k = idx >> 12;
    wt4[idx] = wih[(size_t)(gate * 1024 + j) * 192 + k];
}

// WoutT[k*64+o] = Wout[o*1024+k]
__global__ void build_woutT(const float* __restrict__ wout, float* __restrict__ wt)
{
    int idx = blockIdx.x * 256 + threadIdx.x;   // 65536
    int o = idx & 63, k = idx >> 6;
    wt[idx] = wout[(size_t)o * 1024 + k];
}

// interleaved bias: out[j*4+gate] = a[gate*1024+j] + b[gate*1024+j]
__global__ void build_bias(const float* __restrict__ a, const float* __restrict__ b,
                           float* __restrict__ o)
{
    int idx = blockIdx.x * 256 + threadIdx.x;   // 4096
    int gate = idx & 3, j = idx >> 2;
    int n = gate * 1024 + j;
    o[idx] = a[n] + b[n];
}

// W0[n][0:64] = W_ih0[n][128:192] (y-feedback cols), W0[n][64:1088] = W_hh0[n][:]
__global__ __launch_bounds__(256) void build_w0(
    const float* __restrict__ wih, const float* __restrict__ whh,
    unsigned short* __restrict__ w0)
{
    int idx = blockIdx.x * 256 + threadIdx.x;   // 4096*272 exact
    int n = idx / 272;
    int c = (idx - n * 272) * 4;
    float4 v;
    if (c < 64) v = *(const float4*)(wih + (size_t)n * 192 + 128 + c);
    else        v = *(const float4*)(whh + (size_t)n * 1024 + (c - 64));
    ushort4 o;
    o.x = f2bf(v.x); o.y = f2bf(v.y); o.z = f2bf(v.z); o.w = f2bf(v.w);
    *(ushort4*)(w0 + (size_t)n * KA + c) = o;
}

// W1[n][0:1024] = W_ih1[n][:], W1[n][1024:2048] = W_hh1[n][:]
__global__ __launch_bounds__(256) void build_w1(
    const float* __restrict__ wih, const float* __restrict__ whh,
    unsigned short* __restrict__ w1)
{
    int idx = blockIdx.x * 256 + threadIdx.x;   // 4096*512 exact
    int n = idx >> 9;
    int c = (idx & 511) * 4;
    float4 v;
    if (c < 1024) v = *(const float4*)(wih + (size_t)n * 1024 + c);
    else          v = *(const float4*)(whh + (size_t)n * 1024 + (c - 1024));
    ushort4 o;
    o.x = f2bf(v.x); o.y = f2bf(v.y); o.z = f2bf(v.z); o.w = f2bf(v.w);
    *(ushort4*)(w1 + (size_t)n * KB + c) = o;
}

extern "C" void kernel_launch(void* const* d_in, const int* in_sizes, int n_in,
                              void* d_out, int out_size, void* d_ws, size_t ws_size,
                              hipStream_t stream)
{
    (void)in_sizes; (void)n_in; (void)out_size; (void)ws_size;
    const float* static_in = (const float*)d_in[0];
    const float* Wih0 = (const float*)d_in[1];
    const float* Whh0 = (const float*)d_in[2];
    const float* bih0 = (const float*)d_in[3];
    const float* bhh0 = (const float*)d_in[4];
    const float* Wih1 = (const float*)d_in[5];
    const float* Whh1 = (const float*)d_in[6];
    const float* bih1 = (const float*)d_in[7];
    const float* bhh1 = (const float*)d_in[8];
    const float* Wout = (const float*)d_in[9];
    const float* bout = (const float*)d_in[10];
    float* out = (float*)d_out;

    char* p = (char*)d_ws;
    size_t off = 0;
    auto take = [&](size_t n) { char* r = p + off; off += (n + 255) & ~(size_t)255; return r; };

    unsigned short* W0   = (unsigned short*)take((size_t)4096 * KA * 2);
    unsigned short* W1   = (unsigned short*)take((size_t)4096 * KB * 2);
    float*          B1b  = (float*)take(4096 * 4);
    float*          B0b  = (float*)take(4096 * 4);
    float*          WT0  = (float*)take((size_t)128 * 4096 * 4);
    float*          WoT  = (float*)take((size_t)1024 * 64 * 4);
    float*          S0   = (float*)take((size_t)BATCH * 4096 * 4);
    float*          H2f  = (float*)take((size_t)BATCH * HID * 4);
    float*          C1   = (float*)take((size_t)BATCH * HID * 4);
    float*          C2   = (float*)take((size_t)BATCH * HID * 4);
    unsigned short* X0a  = (unsigned short*)take((size_t)BATCH * KA * 2);
    unsigned short* X0b  = (unsigned short*)take((size_t)BATCH * KA * 2);
    unsigned short* X1a  = (unsigned short*)take((size_t)BATCH * KB * 2);
    unsigned short* X1b  = (unsigned short*)take((size_t)BATCH * KB * 2);
    // total ~190 MiB

    hipMemsetAsync(C1, 0, (size_t)BATCH * HID * 4, stream);
    hipMemsetAsync(C2, 0, (size_t)BATCH * HID * 4, stream);
    hipMemsetAsync(X0a, 0, (size_t)BATCH * KA * 2, stream);   // y0 = h1_0 = 0
    hipMemsetAsync(X1a, 0, (size_t)BATCH * KB * 2, stream);   // h2_0 = 0

    build_w0<<<4352, 256, 0, stream>>>(Wih0, Whh0, W0);
    build_w1<<<8192, 256, 0, stream>>>(Wih1, Whh1, W1);
    build_wt0<<<2048, 256, 0, stream>>>(Wih0, WT0);
    build_woutT<<<256, 256, 0, stream>>>(Wout, WoT);
    build_bias<<<16, 256, 0, stream>>>(bih0, bhh0, B0b);
    build_bias<<<16, 256, 0, stream>>>(bih1, bhh1, B1b);
    s0_gemm_tiled<<<dim3(16, 128), 256, 0, stream>>>(static_in, WT0, B0b, S0);

    dim3 grid(16, 16);   // 256 blocks of 512 thr = exactly 1 per CU
    for (int t = 0; t < TSTEPS; ++t) {
        unsigned short* X0c = (t & 1) ? X0b : X0a;
        unsigned short* X0n = (t & 1) ? X0a : X0b;
        unsigned short* X1c = (t & 1) ? X1b : X1a;
        unsigned short* X1n = (t & 1) ? X1a : X1b;
        // layer 0: gates = X0c @ W0^T + S0[b]; h1 -> X1c[:,0:1024] and X0n[:,64:1088]
        lstm_gate_gemm<<<grid, 512, 0, stream>>>(X0c, KA, W0, S0, 4096, C1,
                                                 X1c, KB, 0, X0n, KA, 64, nullptr);
        // layer 1: gates = X1c @ W1^T + b1 (interleaved); h2 -> X1n[:,1024:2048] + H2f
        lstm_gate_gemm<<<grid, 512, 0, stream>>>(X1c, KB, W1, B1b, 0, C2,
                                                 X1n, KB, 1024, nullptr, 0, 0, H2f);
        // y_t = H2f @ WoutT + bout -> out[:,t,:] and X0n[:,0:64]
        out_gemm<<<512, 256, 0, stream>>>(H2f, WoT, bout, out + t * NOUT, X0n);
    }
}

// Round 9
// 3944.104 us; speedup vs baseline: 1.2468x; 1.1077x over previous
//
#include <hip/hip_runtime.h>

#define BATCH  4096
#define HID    1024
#define NOUT   64
#define TSTEPS 25
#define KA2    1216   // 64 (y_prev) + 128 (static, bf16) + 1024 (h1)
#define KB     2048   // 1024 (h1) + 1024 (h2)
#define LDY    1600   // TSTEPS * NOUT

typedef __attribute__((ext_vector_type(8))) __bf16 bf16x8;
typedef __attribute__((ext_vector_type(4))) float  floatx4;

__device__ __forceinline__ unsigned short f2bf(float f) {
    union { float f; unsigned u; } v; v.f = f;
    unsigned r = v.u + 0x7fffu + ((v.u >> 16) & 1u);
    return (unsigned short)(r >> 16);
}
__device__ __forceinline__ float rcpf(float x) { return __builtin_amdgcn_rcpf(x); }
__device__ __forceinline__ float sigmf(float x) { return rcpf(1.0f + __expf(-x)); }
__device__ __forceinline__ float tanh_fast(float x) {
    float ax = fabsf(x);
    float e  = __expf(-2.0f * ax);
    float t  = (1.0f - e) * rcpf(1.0f + e);
    return copysignf(t, x);
}

#define GLDS16(gp, lp) __builtin_amdgcn_global_load_lds( \
    (const __attribute__((address_space(1))) void*)(gp), \
    (__attribute__((address_space(3))) void*)(lp), 16, 0, 0)

// Fused GEMM + LSTM cell, v7: ILP config. Same traffic-optimal 256x256 block
// tile as v6 (512 MB/dispatch, the best point on the measured wall=a+b*traffic
// line), but 1024 threads / 16 waves of 64x64 (acc[4][4]=64 AGPR + ~56 VGPR
// ~= 120 regs) -> 4 waves/SIMD instead of v6's 2. Attacks the measured fixed
// cost a~67us (latency exposure), not traffic. 2 staging slots/thread.
// LDS dbuf 2x32KB; grid 16x16 = exactly 1 block/CU; XCD round-robin swizzle.
// G = X[4096,K] @ W[4096,K]^T (W rows gate-major: gate*HID + j), then per (b,j):
// gates = G + ginit[j*4+gate] (broadcast bias, gate-interleaved),
// c' = sig(f)*c + sig(i)*tanh(g); h = sig(o)*tanh(c'); h -> d1/d2 (bf16), dfp (fp32).
__global__ __launch_bounds__(1024, 4) void lstm_gate_gemm(
    const unsigned short* __restrict__ X, int K,
    const unsigned short* __restrict__ W,
    const float* __restrict__ ginit,
    float* __restrict__ cell,
    unsigned short* __restrict__ d1, int ld1, int off1,
    unsigned short* __restrict__ d2, int ld2, int off2,
    float* __restrict__ dfp)
{
    // buffer: A(256x32 bf16 = 16K) + B(256x32 = 16K) = 32 KB; two buffers.
    __shared__ __align__(16) char smem[65536];

    const int tid  = threadIdx.x;
    const int lane = tid & 63;
    const int w    = tid >> 6;          // 0..15
    const int q    = lane >> 4;
    const int lr   = lane & 15;
    const int wm   = w >> 2;            // M quarter (64 rows each)
    const int wn   = w & 3;             // N quarter (64 cols each)

    // XCD-aware swizzle: id&7 = XCD (round-robin dispatch), each XCD gets a
    // 4(x) x 8(y) block region, iterated x-fastest (B-tile re-reads adjacent).
    const int id  = blockIdx.y * 16 + blockIdx.x;
    const int xcd = id & 7;
    const int c   = id >> 3;                       // 0..31
    const int bx  = (xcd & 3) * 4 + (c & 3);       // 0..15
    const int by  = (xcd >> 2) * 8 + (c >> 2);     // 0..15
    const int m0  = bx * 256;
    const int j0  = by * 64;

    // staging: slot s (16B): s<1024 -> A row s>>2 (0..255), else B row (s-1024)>>2.
    // k-group (s&3)^((row>>1)&3) xor swizzle. 2 slots per thread.
    const unsigned short* srcS[2];
    char* ldsS[2];
#pragma unroll
    for (int e = 0; e < 2; ++e) {
        int s = e * 1024 + tid;
        if (s < 1024) {
            int row = s >> 2;
            int kg  = (s & 3) ^ ((row >> 1) & 3);
            srcS[e] = X + (size_t)(m0 + row) * K + kg * 8;
        } else {
            int t   = s - 1024;
            int row = t >> 2;
            int kg  = (t & 3) ^ ((row >> 1) & 3);
            int jj = row >> 2, gate = row & 3;
            srcS[e] = W + (size_t)(gate * HID + j0 + jj) * K + kg * 8;
        }
        ldsS[e] = smem + (size_t)s * 16;
    }

    // fragment LDS offsets within a buffer (same swizzle)
    unsigned offA[4], offB[4];
#pragma unroll
    for (int i = 0; i < 4; ++i) {
        int ra = wm * 64 + i * 16 + lr;                  // 0..255
        offA[i] = (unsigned)((ra * 4 + (q ^ ((ra >> 1) & 3))) * 16);
        int rb = wn * 64 + i * 16 + lr;                  // 0..255
        offB[i] = (unsigned)(16384 + (rb * 4 + (q ^ ((rb >> 1) & 3))) * 16);
    }

    floatx4 acc[4][4];
#pragma unroll
    for (int i = 0; i < 4; ++i)
#pragma unroll
        for (int j = 0; j < 4; ++j)
            acc[i][j] = floatx4{0.f, 0.f, 0.f, 0.f};

    const int kiters = K >> 5;

    // prologue: stage kt=0 into buf0
#pragma unroll
    for (int e = 0; e < 2; ++e)
        GLDS16(srcS[e], ldsS[e]);

    for (int kt = 0; kt < kiters; ++kt) {
        __syncthreads();   // drains buf[kt&1] loads (issued one MFMA phase ago)
        const int cur = (kt & 1) * 32768;
        if (kt + 1 < kiters) {
            const int koff = (kt + 1) * 32;
            const int nxt  = ((kt + 1) & 1) * 32768;
#pragma unroll
            for (int e = 0; e < 2; ++e)
                GLDS16(srcS[e] + koff, ldsS[e] + nxt);
        }
        bf16x8 av[4], bv[4];
#pragma unroll
        for (int j = 0; j < 4; ++j) bv[j] = *(const bf16x8*)(smem + cur + offB[j]);
#pragma unroll
        for (int i = 0; i < 4; ++i) av[i] = *(const bf16x8*)(smem + cur + offA[i]);
#pragma unroll
        for (int i = 0; i < 4; ++i)
#pragma unroll
            for (int j = 0; j < 4; ++j)
                acc[i][j] = __builtin_amdgcn_mfma_f32_16x16x32_bf16(av[i], bv[j], acc[i][j], 0, 0, 0);
    }

    // ---- epilogue: per-wave LDS transpose of 16x64 slabs, then cell update.
    // Barriers fence write-phase vs read-phase (compiler memory ordering —
    // scalar float stores vs float4 loads are not TBAA-ordered without them).
    const int jg = j0 + wn * 16 + lr;
    const float4 gi = *(const float4*)(ginit + (size_t)jg * 4);  // broadcast bias (i,f,g,o)
    float* scratch = (float*)(void*)smem + w * 1024;     // 4 KB per wave x16 = 64 KB

#pragma unroll
    for (int i = 0; i < 4; ++i) {
        __syncthreads();
#pragma unroll
        for (int j = 0; j < 4; ++j)
#pragma unroll
            for (int r = 0; r < 4; ++r)
                scratch[(q * 4 + r) * 64 + j * 16 + lr] = acc[i][j][r];  // C/D: row=q*4+r, col=lr
        __syncthreads();
#pragma unroll
        for (int p = 0; p < 4; ++p) {
            int row = q + p * 4;
            const float4 g = *(const float4*)(scratch + row * 64 + lr * 4);  // (i,f,g,o)
            int b = m0 + wm * 64 + i * 16 + row;
            float iv = sigmf(g.x + gi.x);
            float fv = sigmf(g.y + gi.y);
            float gv = tanh_fast(g.z + gi.z);
            float ov = sigmf(g.w + gi.w);
            size_t ci = (size_t)b * HID + jg;
            float cn = fv * cell[ci] + iv * gv;
            cell[ci] = cn;
            float hv = ov * tanh_fast(cn);
            unsigned short hb = f2bf(hv);
            d1[(size_t)b * ld1 + off1 + jg] = hb;
            if (d2)  d2[(size_t)b * ld2 + off2 + jg] = hb;
            if (dfp) dfp[(size_t)b * HID + jg] = hv;
        }
    }
}

// y = h2_f32 @ Wout^T + bout (fp32); WoutT layout wt[k*64+o]; h2 staged in LDS.
__global__ __launch_bounds__(256) void out_gemm(
    const float* __restrict__ h2, const float* __restrict__ wt,
    const float* __restrict__ bout, float* __restrict__ y,
    unsigned short* __restrict__ xn)
{
    __shared__ float hl[8 * 1024];   // 32 KB: 8 h2 rows
    const int tid = threadIdx.x;
    const int b0 = blockIdx.x * 8;
#pragma unroll
    for (int r = 0; r < 8; ++r) {
        int f4 = r * 256 + tid;
        *(float4*)(hl + f4 * 4) = *(const float4*)(h2 + (size_t)b0 * 1024 + f4 * 4);
    }
    __syncthreads();
    const int o  = tid & 63;
    const int wv = tid >> 6;
    float acc0 = 0.f, acc1 = 0.f;
#pragma unroll 8
    for (int k = 0; k < 1024; ++k) {
        float wvv = wt[k * 64 + o];
        acc0 += hl[(wv * 2 + 0) * 1024 + k] * wvv;
        acc1 += hl[(wv * 2 + 1) * 1024 + k] * wvv;
    }
    float bo = bout[o];
    int b = b0 + wv * 2;
    float y0 = acc0 + bo, y1 = acc1 + bo;
    y[(size_t)b * LDY + o] = y0;
    y[(size_t)(b + 1) * LDY + o] = y1;
    xn[(size_t)b * KA2 + o] = f2bf(y0);
    xn[(size_t)(b + 1) * KA2 + o] = f2bf(y1);
}

// WoutT[k*64+o] = Wout[o*1024+k]
__global__ void build_woutT(const float* __restrict__ wout, float* __restrict__ wt)
{
    int idx = blockIdx.x * 256 + threadIdx.x;   // 65536
    int o = idx & 63, k = idx >> 6;
    wt[idx] = wout[(size_t)o * 1024 + k];
}

// interleaved bias: out[j*4+gate] = a[gate*1024+j] + b[gate*1024+j]
__global__ void build_bias(const float* __restrict__ a, const float* __restrict__ b,
                           float* __restrict__ o)
{
    int idx = blockIdx.x * 256 + threadIdx.x;   // 4096
    int gate = idx & 3, j = idx >> 2;
    int n = gate * 1024 + j;
    o[idx] = a[n] + b[n];
}

// W0[n] (KA2=1216): [0:64]=W_ih0[n][128:192] (y cols), [64:192]=W_ih0[n][0:128]
// (static cols), [192:1216]=W_hh0[n][:]
__global__ __launch_bounds__(256) void build_w0(
    const float* __restrict__ wih, const float* __restrict__ whh,
    unsigned short* __restrict__ w0)
{
    int idx = blockIdx.x * 256 + threadIdx.x;   // 4096*304 exact
    int n = idx / 304;
    int c = (idx - n * 304) * 4;
    float4 v;
    if (c < 64)       v = *(const float4*)(wih + (size_t)n * 192 + 128 + c);
    else if (c < 192) v = *(const float4*)(wih + (size_t)n * 192 + (c - 64));
    else              v = *(const float4*)(whh + (size_t)n * 1024 + (c - 192));
    ushort4 o;
    o.x = f2bf(v.x); o.y = f2bf(v.y); o.z = f2bf(v.z); o.w = f2bf(v.w);
    *(ushort4*)(w0 + (size_t)n * KA2 + c) = o;
}

// W1[n][0:1024] = W_ih1[n][:], W1[n][1024:2048] = W_hh1[n][:]
__global__ __launch_bounds__(256) void build_w1(
    const float* __restrict__ wih, const float* __restrict__ whh,
    unsigned short* __restrict__ w1)
{
    int idx = blockIdx.x * 256 + threadIdx.x;   // 4096*512 exact
    int n = idx >> 9;
    int c = (idx & 511) * 4;
    float4 v;
    if (c < 1024) v = *(const float4*)(wih + (size_t)n * 1024 + c);
    else          v = *(const float4*)(whh + (size_t)n * 1024 + (c - 1024));
    ushort4 o;
    o.x = f2bf(v.x); o.y = f2bf(v.y); o.z = f2bf(v.z); o.w = f2bf(v.w);
    *(ushort4*)(w1 + (size_t)n * KB + c) = o;
}

// static bf16 into X0a and X0b cols 64..191
__global__ __launch_bounds__(256) void build_x0static(
    const float* __restrict__ stat, unsigned short* __restrict__ xa,
    unsigned short* __restrict__ xb)
{
    int idx = blockIdx.x * 256 + threadIdx.x;   // 4096*32 exact
    int b = idx >> 5;
    int c = (idx & 31) * 4;
    float4 v = *(const float4*)(stat + (size_t)b * 128 + c);
    ushort4 o;
    o.x = f2bf(v.x); o.y = f2bf(v.y); o.z = f2bf(v.z); o.w = f2bf(v.w);
    *(ushort4*)(xa + (size_t)b * KA2 + 64 + c) = o;
    *(ushort4*)(xb + (size_t)b * KA2 + 64 + c) = o;
}

extern "C" void kernel_launch(void* const* d_in, const int* in_sizes, int n_in,
                              void* d_out, int out_size, void* d_ws, size_t ws_size,
                              hipStream_t stream)
{
    (void)in_sizes; (void)n_in; (void)out_size; (void)ws_size;
    const float* static_in = (const float*)d_in[0];
    const float* Wih0 = (const float*)d_in[1];
    const float* Whh0 = (const float*)d_in[2];
    const float* bih0 = (const float*)d_in[3];
    const float* bhh0 = (const float*)d_in[4];
    const float* Wih1 = (const float*)d_in[5];
    const float* Whh1 = (const float*)d_in[6];
    const float* bih1 = (const float*)d_in[7];
    const float* bhh1 = (const float*)d_in[8];
    const float* Wout = (const float*)d_in[9];
    const float* bout = (const float*)d_in[10];
    float* out = (float*)d_out;

    char* p = (char*)d_ws;
    size_t off = 0;
    auto take = [&](size_t n) { char* r = p + off; off += (n + 255) & ~(size_t)255; return r; };

    unsigned short* W0   = (unsigned short*)take((size_t)4096 * KA2 * 2);
    unsigned short* W1   = (unsigned short*)take((size_t)4096 * KB * 2);
    float*          B1b  = (float*)take(4096 * 4);
    float*          B0b  = (float*)take(4096 * 4);
    float*          WoT  = (float*)take((size_t)1024 * 64 * 4);
    float*          H2f  = (float*)take((size_t)BATCH * HID * 4);
    float*          C1   = (float*)take((size_t)BATCH * HID * 4);
    float*          C2   = (float*)take((size_t)BATCH * HID * 4);
    unsigned short* X0a  = (unsigned short*)take((size_t)BATCH * KA2 * 2);
    unsigned short* X0b  = (unsigned short*)take((size_t)BATCH * KA2 * 2);
    unsigned short* X1a  = (unsigned short*)take((size_t)BATCH * KB * 2);
    unsigned short* X1b  = (unsigned short*)take((size_t)BATCH * KB * 2);
    // total ~130 MiB

    hipMemsetAsync(C1, 0, (size_t)BATCH * HID * 4, stream);
    hipMemsetAsync(C2, 0, (size_t)BATCH * HID * 4, stream);
    hipMemsetAsync(X0a, 0, (size_t)BATCH * KA2 * 2, stream);  // y0 = h1_0 = 0
    hipMemsetAsync(X0b, 0, (size_t)BATCH * KA2 * 2, stream);
    hipMemsetAsync(X1a, 0, (size_t)BATCH * KB * 2, stream);   // h2_0 = 0

    build_w0<<<4864, 256, 0, stream>>>(Wih0, Whh0, W0);
    build_w1<<<8192, 256, 0, stream>>>(Wih1, Whh1, W1);
    build_woutT<<<256, 256, 0, stream>>>(Wout, WoT);
    build_bias<<<16, 256, 0, stream>>>(bih0, bhh0, B0b);
    build_bias<<<16, 256, 0, stream>>>(bih1, bhh1, B1b);
    build_x0static<<<512, 256, 0, stream>>>(static_in, X0a, X0b);

    dim3 grid(16, 16);   // 256 blocks of 1024 thr = exactly 1 per CU
    for (int t = 0; t < TSTEPS; ++t) {
        unsigned short* X0c = (t & 1) ? X0b : X0a;
        unsigned short* X0n = (t & 1) ? X0a : X0b;
        unsigned short* X1c = (t & 1) ? X1b : X1a;
        unsigned short* X1n = (t & 1) ? X1a : X1b;
        // layer 0: gates = X0c @ W0^T + b0; h1 -> X1c[:,0:1024] and X0n[:,192:1216]
        lstm_gate_gemm<<<grid, 1024, 0, stream>>>(X0c, KA2, W0, B0b, C1,
                                                  X1c, KB, 0, X0n, KA2, 192, nullptr);
        // layer 1: gates = X1c @ W1^T + b1; h2 -> X1n[:,1024:2048] + H2f
        lstm_gate_gemm<<<grid, 1024, 0, stream>>>(X1c, KB, W1, B1b, C2,
                                                  X1n, KB, 1024, nullptr, 0, 0, H2f);
        // y_t = H2f @ WoutT + bout -> out[:,t,:] and X0n[:,0:64]
        out_gemm<<<512, 256, 0, stream>>>(H2f, WoT, bout, out + t * NOUT, X0n);
    }
}